// Round 5
// baseline (182.890 us; speedup 1.0000x reference)
//
#include <hip/hip_runtime.h>
#include <hip/hip_bf16.h>

// out[b,o] = sum_i x[b,i]*w[o,i] + bias[o]; M=4096, N=2048, K=2048, fp32 io.
// R5: split-K=2. R4 (4-wave 64x64 wave-tiles) has the lowest LDS-read floor
// (1.05 GB device ~20us) but only 2 blocks/CU (grid 512) -> barrier drains
// exposed. Split K into 2 halves: grid 1024 = 4 blocks/CU, 16 waves/CU,
// same LDS traffic. Epilogue: atomicAdd f32 onto memset(0) output; the
// kh==0 block adds bias. hipMemsetAsync is graph-capture-safe.

#define M_DIM 4096
#define N_DIM 2048
#define K_DIM 2048
#define BK 64
#define KSPLIT 2
#define KHALF (K_DIM / KSPLIT)   // 1024
#define TILES 512                // (M/128)*(N/128)

typedef unsigned short ushort_t;
typedef __attribute__((ext_vector_type(8))) short short8;      // 8 bf16 (A/B frag)
typedef __attribute__((ext_vector_type(4))) float float4v;     // C/D frag
typedef __attribute__((ext_vector_type(8))) unsigned short ushort8;

// ---------------- fp32 -> bf16 (RNE), x and w fused in one launch ----------------
__device__ __forceinline__ unsigned short f2bf_rne(float f) {
    unsigned int u = __builtin_bit_cast(unsigned int, f);
    u += 0x7FFFu + ((u >> 16) & 1u);
    return (unsigned short)(u >> 16);
}

__global__ void __launch_bounds__(256) cvt_both(const float* __restrict__ x,
                                                const float* __restrict__ w,
                                                ushort8* __restrict__ ws8,
                                                int xN8, int totN8) {
    int idx = blockIdx.x * 256 + threadIdx.x;
    if (idx >= totN8) return;
    const float4v* in4 = (idx < xN8) ? (const float4v*)x + (size_t)idx * 2
                                     : (const float4v*)w + (size_t)(idx - xN8) * 2;
    float4v a = in4[0];
    float4v b = in4[1];
    ushort8 r;
    r[0] = f2bf_rne(a[0]); r[1] = f2bf_rne(a[1]);
    r[2] = f2bf_rne(a[2]); r[3] = f2bf_rne(a[3]);
    r[4] = f2bf_rne(b[0]); r[5] = f2bf_rne(b[1]);
    r[6] = f2bf_rne(b[2]); r[7] = f2bf_rne(b[3]);
    ws8[idx] = r;
}

// ---------------- async global -> LDS (16B per lane; dest = base + lane*16) ----
__device__ __forceinline__ void async_load16(const void* g, void* l) {
    __builtin_amdgcn_global_load_lds(
        (const __attribute__((address_space(1))) void*)(g),
        (__attribute__((address_space(3))) void*)(l), 16, 0, 0);
}

// ---------------- bf16 MFMA GEMM, out += Xb * Wb^T (+ bias on kh==0) ----------
// Xb: [M,K] bf16 row-major, Wb: [N,K] bf16 row-major.
// Block: 128x128 tile, 256 threads = 4 waves (2x2), wave-tile 64x64.
// blockIdx.x: bits [8:0] = tile, bit 9 = k-half.
__global__ void __launch_bounds__(256) gemm_bf16(const ushort_t* __restrict__ xb,
                                                 const ushort_t* __restrict__ wb,
                                                 const float* __restrict__ bias,
                                                 float* __restrict__ out) {
    __shared__ ushort_t ldsA[128 * BK];   // 16 KB
    __shared__ ushort_t ldsB[128 * BK];   // 16 KB

    const int tid  = threadIdx.x;
    const int wave = tid >> 6;     // 0..3
    const int lane = tid & 63;
    const int quad = lane >> 4;    // 0..3
    const int lrow = lane & 15;    // 0..15

    const int tile = blockIdx.x & (TILES - 1);
    const int kh   = blockIdx.x >> 9;        // 0 or 1
    const int bm = tile >> 4;    // 0..31
    const int bn = tile & 15;    // 0..15
    const int rowBase = bm * 128;
    const int colBase = bn * 128;
    const int kOff = kh * KHALF;

    const int waveR = (wave >> 1) * 64;   // 0 or 64
    const int waveC = (wave & 1) * 64;    // 0 or 64

    // ---- staging: each wave stages 32 rows of A AND 32 rows of B ----
    // Each instr covers 8 rows (64 lanes x 16B / 128B rows).
    // Lane L -> row (L>>3), stored position (L&7); fetch global chunk
    // q = (L&7) ^ (L>>3)  => stored chunk at position p of row r is p^(r&7).
    const int R0 = wave * 32;
    const int q  = (lane & 7) ^ (lane >> 3);
    const ushort_t* gA0 = xb + (long long)(rowBase + R0 + (lane >> 3)) * K_DIM + kOff + q * 8;
    const ushort_t* gA1 = gA0 + (long long)8  * K_DIM;
    const ushort_t* gA2 = gA0 + (long long)16 * K_DIM;
    const ushort_t* gA3 = gA0 + (long long)24 * K_DIM;
    const ushort_t* gB0 = wb + (long long)(colBase + R0 + (lane >> 3)) * K_DIM + kOff + q * 8;
    const ushort_t* gB1 = gB0 + (long long)8  * K_DIM;
    const ushort_t* gB2 = gB0 + (long long)16 * K_DIM;
    const ushort_t* gB3 = gB0 + (long long)24 * K_DIM;
    ushort_t* lA = ldsA + R0 * BK;   // wave-uniform
    ushort_t* lB = ldsB + R0 * BK;

    // ---- fragment read offsets ----
    // Row r = waveR/C + mi*16 + lrow; chunk c (k-half 0: c=quad, half 1: c=quad+4)
    // stored at position c ^ (r&7) = c ^ (lrow&7). (quad+4)^s = (quad^s)^4 -> ^32 shorts.
    const int sw0 = (quad ^ (lrow & 7)) * 8;
    const ushort_t* aP = &ldsA[(waveR + lrow) * BK];
    const ushort_t* bP = &ldsB[(waveC + lrow) * BK];

    float4v acc[4][4] = {};

    for (int k0 = 0; k0 < KHALF; k0 += BK) {
        async_load16(gA0, lA);
        async_load16(gA1, lA + 8  * BK);
        async_load16(gA2, lA + 16 * BK);
        async_load16(gA3, lA + 24 * BK);
        async_load16(gB0, lB);
        async_load16(gB1, lB + 8  * BK);
        async_load16(gB2, lB + 16 * BK);
        async_load16(gB3, lB + 24 * BK);
        gA0 += BK; gA1 += BK; gA2 += BK; gA3 += BK;
        gB0 += BK; gB1 += BK; gB2 += BK; gB3 += BK;
        __syncthreads();

        short8 af0[4], af1[4], bf0[4], bf1[4];
#pragma unroll
        for (int mi = 0; mi < 4; mi++) {
            af0[mi] = *(const short8*)(aP + mi * 16 * BK + sw0);
            af1[mi] = *(const short8*)(aP + mi * 16 * BK + (sw0 ^ 32));
        }
#pragma unroll
        for (int ni = 0; ni < 4; ni++) {
            bf0[ni] = *(const short8*)(bP + ni * 16 * BK + sw0);
            bf1[ni] = *(const short8*)(bP + ni * 16 * BK + (sw0 ^ 32));
        }
#pragma unroll
        for (int mi = 0; mi < 4; mi++)
#pragma unroll
            for (int ni = 0; ni < 4; ni++)
                acc[mi][ni] = __builtin_amdgcn_mfma_f32_16x16x32_bf16(
                    af0[mi], bf0[ni], acc[mi][ni], 0, 0, 0);
#pragma unroll
        for (int mi = 0; mi < 4; mi++)
#pragma unroll
            for (int ni = 0; ni < 4; ni++)
                acc[mi][ni] = __builtin_amdgcn_mfma_f32_16x16x32_bf16(
                    af1[mi], bf1[ni], acc[mi][ni], 0, 0, 0);
        __syncthreads();
    }

    // ---- epilogue: C/D layout col=lane&15, row=quad*4+reg; atomic accumulate ----
#pragma unroll
    for (int ni = 0; ni < 4; ni++) {
        const int col = colBase + waveC + ni * 16 + lrow;
        const float bv = (kh == 0) ? bias[col] : 0.0f;
#pragma unroll
        for (int mi = 0; mi < 4; mi++) {
            const int row0 = rowBase + waveR + mi * 16 + quad * 4;
            float4v v = acc[mi][ni];
#pragma unroll
            for (int i = 0; i < 4; i++)
                atomicAdd(&out[(long long)(row0 + i) * N_DIM + col], v[i] + bv);
        }
    }
}

// ---------------- fallback (ws too small): fp32 naive ----------------
__global__ void __launch_bounds__(256) linear_naive(const float* __restrict__ x,
                                                    const float* __restrict__ w,
                                                    const float* __restrict__ bias,
                                                    float* __restrict__ out) {
    __shared__ float xs[K_DIM];
    const int b = blockIdx.y;
    const int o = blockIdx.x * 256 + threadIdx.x;
    for (int k = threadIdx.x; k < K_DIM; k += 256)
        xs[k] = x[(long long)b * K_DIM + k];
    __syncthreads();
    const float4v* wr = (const float4v*)(w + (long long)o * K_DIM);
    float s = 0.f;
    for (int k4 = 0; k4 < K_DIM / 4; k4++) {
        float4v wv = wr[k4];
        float4v xv = *(const float4v*)&xs[k4 * 4];
        s += xv[0] * wv[0] + xv[1] * wv[1] + xv[2] * wv[2] + xv[3] * wv[3];
    }
    out[(long long)b * N_DIM + o] = s + bias[o];
}

extern "C" void kernel_launch(void* const* d_in, const int* in_sizes, int n_in,
                              void* d_out, int out_size, void* d_ws, size_t ws_size,
                              hipStream_t stream) {
    const float* x    = (const float*)d_in[0];   // [4096, 2048]
    const float* w    = (const float*)d_in[1];   // [2048, 2048]
    const float* bias = (const float*)d_in[2];   // [2048]
    float* out = (float*)d_out;                  // [4096, 2048]

    const size_t xElems = (size_t)M_DIM * K_DIM;   // 8388608
    const size_t wElems = (size_t)N_DIM * K_DIM;   // 4194304
    const size_t need = (xElems + wElems) * sizeof(ushort_t);  // ~25.2 MB

    if (ws_size >= need) {
        ushort_t* xb = (ushort_t*)d_ws;
        ushort_t* wb = xb + xElems;
        const int xN8 = (int)(xElems / 8);
        const int totN8 = (int)((xElems + wElems) / 8);
        hipMemsetAsync(d_out, 0, (size_t)M_DIM * N_DIM * sizeof(float), stream);
        cvt_both<<<(totN8 + 255) / 256, 256, 0, stream>>>(x, w, (ushort8*)d_ws, xN8, totN8);
        gemm_bf16<<<TILES * KSPLIT, 256, 0, stream>>>(xb, wb, bias, out);
    } else {
        dim3 grid(N_DIM / 256, M_DIM);
        linear_naive<<<grid, 256, 0, stream>>>(x, w, bias, out);
    }
}

// Round 6
// 130.483 us; speedup vs baseline: 1.4016x; 1.4016x over previous
//
#include <hip/hip_runtime.h>
#include <hip/hip_bf16.h>

// out[b,o] = sum_i x[b,i]*w[o,i] + bias[o]; M=4096, N=2048, K=2048, fp32 io.
// R6: revert R5's split-K/atomics (L2 atomic serialization doubled gemm).
// Back to R3 (best: 512thr, 8 waves x 64x32 wave-tile, 2 blocks/CU,
// 16 waves/CU) and raise BK 64 -> 128: 16 K-iters, halving the number of
// vmcnt(0) barrier drains (the knob that won R2->R3). LDS 64KB/block,
// 2 blocks resident = 128/160KB. Swizzle for 256B rows: chunk c of row r
// stored at position c ^ (r&15).

#define M_DIM 4096
#define N_DIM 2048
#define K_DIM 2048
#define BK 128

typedef unsigned short ushort_t;
typedef __attribute__((ext_vector_type(8))) short short8;      // 8 bf16 (A/B frag)
typedef __attribute__((ext_vector_type(4))) float float4v;     // C/D frag
typedef __attribute__((ext_vector_type(8))) unsigned short ushort8;

// ---------------- fp32 -> bf16 (RNE), x and w fused in one launch ----------------
__device__ __forceinline__ unsigned short f2bf_rne(float f) {
    unsigned int u = __builtin_bit_cast(unsigned int, f);
    u += 0x7FFFu + ((u >> 16) & 1u);
    return (unsigned short)(u >> 16);
}

__global__ void __launch_bounds__(256) cvt_both(const float* __restrict__ x,
                                                const float* __restrict__ w,
                                                ushort8* __restrict__ ws8,
                                                int xN8, int totN8) {
    int idx = blockIdx.x * 256 + threadIdx.x;
    if (idx >= totN8) return;
    const float4v* in4 = (idx < xN8) ? (const float4v*)x + (size_t)idx * 2
                                     : (const float4v*)w + (size_t)(idx - xN8) * 2;
    float4v a = in4[0];
    float4v b = in4[1];
    ushort8 r;
    r[0] = f2bf_rne(a[0]); r[1] = f2bf_rne(a[1]);
    r[2] = f2bf_rne(a[2]); r[3] = f2bf_rne(a[3]);
    r[4] = f2bf_rne(b[0]); r[5] = f2bf_rne(b[1]);
    r[6] = f2bf_rne(b[2]); r[7] = f2bf_rne(b[3]);
    ws8[idx] = r;
}

// ---------------- async global -> LDS (16B per lane; dest = base + lane*16) ----
__device__ __forceinline__ void async_load16(const void* g, void* l) {
    __builtin_amdgcn_global_load_lds(
        (const __attribute__((address_space(1))) void*)(g),
        (__attribute__((address_space(3))) void*)(l), 16, 0, 0);
}

// ---------------- bf16 MFMA GEMM, C = Xb * Wb^T + bias ----------------
// Xb: [M,K] bf16 row-major, Wb: [N,K] bf16 row-major.
// Block: 128x128 tile, 512 threads = 8 waves in 2(row) x 4(col); wave-tile 64x32.
__global__ void __launch_bounds__(512) gemm_bf16(const ushort_t* __restrict__ xb,
                                                 const ushort_t* __restrict__ wb,
                                                 const float* __restrict__ bias,
                                                 float* __restrict__ out) {
    __shared__ ushort_t ldsA[128 * BK];   // 32 KB
    __shared__ ushort_t ldsB[128 * BK];   // 32 KB

    const int tid  = threadIdx.x;
    const int wave = tid >> 6;
    const int lane = tid & 63;
    const int quad = lane >> 4;    // 0..3
    const int lrow = lane & 15;    // 0..15

    const int bm = blockIdx.x >> 4;    // 0..31
    const int bn = blockIdx.x & 15;    // 0..15
    const int rowBase = bm * 128;
    const int colBase = bn * 128;

    const int waveR = (wave >> 2) * 64;   // 0 or 64
    const int waveC = (wave & 3) * 32;    // 0,32,64,96

    // ---- staging: waves 0-3 stage A rows sgrp*32..+31, waves 4-7 stage B ----
    // Rows are 256B = 16 chunks of 16B; one instr covers 4 rows.
    // HW places lane L at row_local L>>4, position L&15. Stored chunk at
    // position p of row r is p ^ (r&15), so instr j (rows R0+4j..+3) lane L
    // fetches global chunk q = (L&15) ^ (L>>4) ^ ((4j)&15).
    const int  sgrp = wave & 3;
    const bool isB  = wave >= 4;
    const int  R0   = sgrp * 32;
    const int  rowl = lane >> 4;          // 0..3
    const int  qb   = (lane & 15) ^ rowl;
    const ushort_t* src = isB ? wb + (long long)colBase * K_DIM
                              : xb + (long long)rowBase * K_DIM;
    const ushort_t* g[8];
#pragma unroll
    for (int j = 0; j < 8; j++)
        g[j] = src + (long long)(R0 + 4 * j + rowl) * K_DIM + (qb ^ ((4 * j) & 15)) * 8;
    ushort_t* lbase = (isB ? ldsB : ldsA) + R0 * BK;  // wave-uniform

    // ---- fragment read offsets ----
    // Row r = waveR/C + mi*16 + lrow -> r&15 = lrow. Chunk c = kc*4 + quad,
    // stored at (kc*4 ^ quad ^ lrow); ushort offset = that * 8 = sw ^ (kc*32).
    const int sw = (quad ^ lrow) * 8;
    const ushort_t* aP = &ldsA[(waveR + lrow) * BK];
    const ushort_t* bP = &ldsB[(waveC + lrow) * BK];

    float4v acc[4][2] = {};

    for (int k0 = 0; k0 < K_DIM; k0 += BK) {
#pragma unroll
        for (int j = 0; j < 8; j++) {
            async_load16(g[j], lbase + (4 * j) * BK);
            g[j] += BK;
        }
        __syncthreads();

#pragma unroll
        for (int kc = 0; kc < 4; kc++) {
            const int ko = sw ^ (kc * 32);
            short8 af[4], bf[2];
#pragma unroll
            for (int mi = 0; mi < 4; mi++)
                af[mi] = *(const short8*)(aP + mi * 16 * BK + ko);
#pragma unroll
            for (int ni = 0; ni < 2; ni++)
                bf[ni] = *(const short8*)(bP + ni * 16 * BK + ko);
#pragma unroll
            for (int mi = 0; mi < 4; mi++)
#pragma unroll
                for (int ni = 0; ni < 2; ni++)
                    acc[mi][ni] = __builtin_amdgcn_mfma_f32_16x16x32_bf16(
                        af[mi], bf[ni], acc[mi][ni], 0, 0, 0);
        }
        __syncthreads();
    }

    // ---- epilogue: C/D layout col=lane&15, row=quad*4+reg ----
#pragma unroll
    for (int ni = 0; ni < 2; ni++) {
        const int col = colBase + waveC + ni * 16 + lrow;
        const float bv = bias[col];
#pragma unroll
        for (int mi = 0; mi < 4; mi++) {
            const int row0 = rowBase + waveR + mi * 16 + quad * 4;
            float4v v = acc[mi][ni];
#pragma unroll
            for (int i = 0; i < 4; i++)
                out[(long long)(row0 + i) * N_DIM + col] = v[i] + bv;
        }
    }
}

// ---------------- fallback (ws too small): fp32 naive ----------------
__global__ void __launch_bounds__(256) linear_naive(const float* __restrict__ x,
                                                    const float* __restrict__ w,
                                                    const float* __restrict__ bias,
                                                    float* __restrict__ out) {
    __shared__ float xs[K_DIM];
    const int b = blockIdx.y;
    const int o = blockIdx.x * 256 + threadIdx.x;
    for (int k = threadIdx.x; k < K_DIM; k += 256)
        xs[k] = x[(long long)b * K_DIM + k];
    __syncthreads();
    const float4v* wr = (const float4v*)(w + (long long)o * K_DIM);
    float s = 0.f;
    for (int k4 = 0; k4 < K_DIM / 4; k4++) {
        float4v wv = wr[k4];
        float4v xv = *(const float4v*)&xs[k4 * 4];
        s += xv[0] * wv[0] + xv[1] * wv[1] + xv[2] * wv[2] + xv[3] * wv[3];
    }
    out[(long long)b * N_DIM + o] = s + bias[o];
}

extern "C" void kernel_launch(void* const* d_in, const int* in_sizes, int n_in,
                              void* d_out, int out_size, void* d_ws, size_t ws_size,
                              hipStream_t stream) {
    const float* x    = (const float*)d_in[0];   // [4096, 2048]
    const float* w    = (const float*)d_in[1];   // [2048, 2048]
    const float* bias = (const float*)d_in[2];   // [2048]
    float* out = (float*)d_out;                  // [4096, 2048]

    const size_t xElems = (size_t)M_DIM * K_DIM;   // 8388608
    const size_t wElems = (size_t)N_DIM * K_DIM;   // 4194304
    const size_t need = (xElems + wElems) * sizeof(ushort_t);  // ~25.2 MB

    if (ws_size >= need) {
        ushort_t* xb = (ushort_t*)d_ws;
        ushort_t* wb = xb + xElems;
        const int xN8 = (int)(xElems / 8);
        const int totN8 = (int)((xElems + wElems) / 8);
        cvt_both<<<(totN8 + 255) / 256, 256, 0, stream>>>(x, w, (ushort8*)d_ws, xN8, totN8);
        gemm_bf16<<<(M_DIM / 128) * (N_DIM / 128), 512, 0, stream>>>(xb, wb, bias, out);
    } else {
        dim3 grid(N_DIM / 256, M_DIM);
        linear_naive<<<grid, 256, 0, stream>>>(x, w, bias, out);
    }
}